// Round 17
// baseline (131.451 us; speedup 1.0000x reference)
//
#include <hip/hip_runtime.h>
#include <hip/hip_bf16.h>
#include <hip/hip_fp8.h>
#include <stdint.h>
#include <math.h>

#define NN 16384
#define DD 256
#define MARGIN_F 0.2f

typedef __attribute__((ext_vector_type(8))) int int32x8;
typedef __attribute__((ext_vector_type(4))) float f32x4;

// monotone order-preserving float<->uint key (max via unsigned atomicMax)
__device__ inline unsigned fkey(float f) {
    unsigned b = __float_as_uint(f);
    return (b & 0x80000000u) ? ~b : (b | 0x80000000u);
}
__device__ inline float fdec(unsigned k) {
    return __uint_as_float((k & 0x80000000u) ? (k ^ 0x80000000u) : ~k);
}
#define NEG_INF_KEY 0x007FFFFFu   // fkey(-inf)

__device__ inline void gload16(const void* g, void* l) {
    __builtin_amdgcn_global_load_lds(
        (const __attribute__((address_space(1))) void*)g,
        (__attribute__((address_space(3))) void*)l, 16, 0, 0);
}

__device__ inline unsigned pk8(float4 v) {
    __hip_fp8_e4m3 q0(v.x), q1(v.y), q2(v.z), q3(v.w);
    return (unsigned)q0.__x | ((unsigned)q1.__x << 8) |
           ((unsigned)q2.__x << 16) | ((unsigned)q3.__x << 24);
}

// ---------------- fused prep: f32->fp8 e4m3 + diag + init maxes ------------
__global__ __launch_bounds__(256) void fused_prep_kernel(
    const float* __restrict__ imgs, const float* __restrict__ caps,
    unsigned char* __restrict__ imgs8, unsigned char* __restrict__ caps8,
    float* __restrict__ diag, unsigned* __restrict__ rowmax,
    unsigned* __restrict__ colmax) {
    const int i = (blockIdx.x << 2) + (threadIdx.x >> 6);
    const int l = threadIdx.x & 63;
    const float4* a4 = reinterpret_cast<const float4*>(imgs + (size_t)i * DD);
    const float4* b4 = reinterpret_cast<const float4*>(caps + (size_t)i * DD);
    float4 av = a4[l];
    float4 bv = b4[l];
    reinterpret_cast<unsigned*>(imgs8 + (size_t)i * DD)[l] = pk8(av);
    reinterpret_cast<unsigned*>(caps8 + (size_t)i * DD)[l] = pk8(bv);
    float s = av.x * bv.x + av.y * bv.y + av.z * bv.z + av.w * bv.w;
    #pragma unroll
    for (int off = 32; off > 0; off >>= 1) s += __shfl_down(s, off);
    if (l == 0) {
        diag[i] = s;
        rowmax[i] = NEG_INF_KEY;
        colmax[i] = NEG_INF_KEY;
    }
}

// ---------------- main: MX-fp8, tall wave tiles + deferred colmax ----------
// R16 skeleton (proven 93us): 512 blocks = 128 row-panels(128) x 4 strips;
// A panel -> af[8][2] (64 VGPRs, full 128 rows/wave); B 64-col chunks dbuf'd
// in [0,32K); barrier pair + counted vmcnt(4); wave owns one 16-col slice.
// NEW: per-chunk colmax does only the per-lane 32->1 max3 tree; the cross-
// lane shfls + clds rmw for chunk h-1 issue at the TOP of chunk h, where
// they overlap the ds_reads/MFMA burst instead of serializing after it.
__global__ __launch_bounds__(256, 2) void score_max_kernel(
    const unsigned char* __restrict__ imgs8,
    const unsigned char* __restrict__ caps8,
    const float* __restrict__ diag,
    unsigned* __restrict__ rowmax, unsigned* __restrict__ colmax) {

    __shared__ char lds[49152];   // [0,32K): A then B dbuf; [32K,48K): clds
    float* clds = reinterpret_cast<float*>(lds + 32768);

    const int bid   = blockIdx.x;
    const int panel = bid >> 2;
    const int strip = bid & 3;
    const int brow  = panel << 7;       // 128-row panel
    const int scol  = strip << 12;      // 4096-col strip

    const int t    = threadIdx.x;
    const int wid  = t >> 6;      // 0..3: col-slice owner
    const int lane = t & 63;
    const int rg   = lane >> 4;   // 0..3
    const int cl   = lane & 15;   // 0..15

    // ---- init clds (4096 floats) ----
    #pragma unroll
    for (int i = 0; i < 16; ++i) clds[t + (i << 8)] = -INFINITY;

    // ---- staging geometry (32B-pair XOR swizzle, row&7) ----
    const int sl = t & 15;
    const int rw = t >> 4;        // 0..15
    const int srcoff = (((sl >> 1) ^ (rw & 7)) << 5) + ((sl & 1) << 4);

    // ---- stage A panel (128 rows = 32KB) into [0,32K) ----
    {
        const unsigned char* src =
            imgs8 + (((size_t)(brow + rw)) << 8) + srcoff;
        #pragma unroll
        for (int i = 0; i < 8; ++i)
            gload16(src + ((size_t)i << 12), lds + t * 16 + i * 4096);
    }
    __syncthreads();

    // ---- A fragments: af[m][ks], row = m*16+cl (full 128 rows/wave) ----
    int32x8 af[8][2];
    #pragma unroll
    for (int m = 0; m < 8; ++m) {
        const int row = m * 16 + cl;
        #pragma unroll
        for (int ks = 0; ks < 2; ++ks)
            af[m][ks] = *reinterpret_cast<const int32x8*>(
                lds + row * 256 + (((rg + (ks << 2)) ^ (cl & 7)) << 5));
    }
    __syncthreads();   // done reading A before B dbuf overwrites [0,32K)

    // stage one 64-col chunk (16KB): 4 gloads/thread
    #define STAGEB(bo, cb) {                                                   \
        const unsigned char* s_ =                                              \
            caps8 + (((size_t)((cb) + rw)) << 8) + srcoff;                     \
        _Pragma("unroll")                                                      \
        for (int i_ = 0; i_ < 4; ++i_)                                         \
            gload16(s_ + ((size_t)i_ << 12), lds + (bo) + t * 16 + i_ * 4096); \
    }

    // prologue: issue stage(0) into buf0
    STAGEB(0, scol);

    float rmx[8][4];
    #pragma unroll
    for (int m = 0; m < 8; ++m)
        #pragma unroll
        for (int r = 0; r < 4; ++r) rmx[m][r] = -INFINITY;

    // ---- B fragment offsets: this wave reads rows (cols) wid*16+cl ----
    const int rr = (wid << 4) + cl;
    unsigned boff[2];
    #pragma unroll
    for (int ks = 0; ks < 2; ++ks)
        boff[ks] = rr * 256 + (((rg + (ks << 2)) ^ (cl & 7)) << 5);

    const f32x4 zv = (f32x4){0.f, 0.f, 0.f, 0.f};
    #define SCL 0x7F7F7F7F   // E8M0 exponent 127 = 1.0 in every byte

    float vprev = -INFINITY;     // deferred per-lane colmax of chunk h-1
    int   cprev = -1;            // its clds index

    for (int h = 0; h < 64; ++h) {
        const int cb = scol + (h << 6);
        const int bo = (h & 1) << 14;

        // barrier 1: all waves done reading buf[(h+1)&1] (chunk h-1)
        __builtin_amdgcn_s_barrier();
        if (h < 63) {
            STAGEB(bo ^ 16384, cb + 64);
            asm volatile("s_waitcnt vmcnt(4)" ::: "memory");
        } else {
            asm volatile("s_waitcnt vmcnt(0)" ::: "memory");
        }
        // barrier 2: stage(h) visible to all waves
        __builtin_amdgcn_s_barrier();

        // ---- deferred cross-lane colmax of chunk h-1 (no dependents:
        //      overlaps the ds_reads + MFMA burst below) ----
        if (h > 0) {
            float vv = vprev;
            vv = fmaxf(vv, __shfl_xor(vv, 16));
            vv = fmaxf(vv, __shfl_xor(vv, 32));
            if (rg == 0) clds[cprev] = fmaxf(clds[cprev], vv);
        }

        const char* buf = lds + bo;
        int32x8 b0 = *reinterpret_cast<const int32x8*>(buf + boff[0]);
        int32x8 b1 = *reinterpret_cast<const int32x8*>(buf + boff[1]);

        f32x4 acc[8];
        __builtin_amdgcn_s_setprio(1);
        #pragma unroll
        for (int m = 0; m < 8; ++m)
            acc[m] = __builtin_amdgcn_mfma_scale_f32_16x16x128_f8f6f4(
                af[m][0], b0, zv, 0, 0, 0, SCL, 0, SCL);
        #pragma unroll
        for (int m = 0; m < 8; ++m)
            acc[m] = __builtin_amdgcn_mfma_scale_f32_16x16x128_f8f6f4(
                af[m][1], b1, acc[m], 0, 0, 0, SCL, 0, SCL);
        __builtin_amdgcn_s_setprio(0);

        // ---- diagonal fix (exact f32); wave's cols = cfb..cfb+15 ----
        const int cfb = cb + (wid << 4);
        if (cfb < brow + 128 && cfb + 16 > brow) {
            #pragma unroll
            for (int m = 0; m < 8; ++m)
                #pragma unroll
                for (int r = 0; r < 4; ++r) {
                    const int gi = brow + m * 16 + (rg << 2) + r;
                    if (gi - cfb == cl) acc[m][r] = -diag[gi];
                }
        }

        // ---- running row-max ----
        #pragma unroll
        for (int m = 0; m < 8; ++m)
            #pragma unroll
            for (int r = 0; r < 4; ++r)
                rmx[m][r] = fmaxf(rmx[m][r], acc[m][r]);

        // ---- per-lane colmax tree (max3-shaped); cross-lane deferred ----
        {
            float p0 = fmaxf(fmaxf(acc[0][0], acc[0][1]), acc[0][2]);
            float p1 = fmaxf(fmaxf(acc[0][3], acc[1][0]), acc[1][1]);
            float p2 = fmaxf(fmaxf(acc[1][2], acc[1][3]), acc[2][0]);
            float p3 = fmaxf(fmaxf(acc[2][1], acc[2][2]), acc[2][3]);
            float p4 = fmaxf(fmaxf(acc[3][0], acc[3][1]), acc[3][2]);
            float p5 = fmaxf(fmaxf(acc[3][3], acc[4][0]), acc[4][1]);
            float p6 = fmaxf(fmaxf(acc[4][2], acc[4][3]), acc[5][0]);
            float p7 = fmaxf(fmaxf(acc[5][1], acc[5][2]), acc[5][3]);
            float p8 = fmaxf(fmaxf(acc[6][0], acc[6][1]), acc[6][2]);
            float p9 = fmaxf(fmaxf(acc[6][3], acc[7][0]), acc[7][1]);
            float pa = fmaxf(fmaxf(acc[7][2], acc[7][3]), p0);
            float q0 = fmaxf(fmaxf(p1, p2), p3);
            float q1 = fmaxf(fmaxf(p4, p5), p6);
            float q2 = fmaxf(fmaxf(p7, p8), p9);
            vprev = fmaxf(fmaxf(q0, q1), fmaxf(q2, pa));
            cprev = cfb + cl - scol;
        }
    }

    // ---- tail: flush chunk 63's deferred colmax ----
    {
        float vv = vprev;
        vv = fmaxf(vv, __shfl_xor(vv, 16));
        vv = fmaxf(vv, __shfl_xor(vv, 32));
        if (rg == 0) clds[cprev] = fmaxf(clds[cprev], vv);
    }

    // ---- row-max writeout (4 waves cover same rows -> global atomic) ----
    #pragma unroll
    for (int m = 0; m < 8; ++m)
        #pragma unroll
        for (int r = 0; r < 4; ++r) {
            float v = rmx[m][r];
            v = fmaxf(v, __shfl_xor(v, 1));
            v = fmaxf(v, __shfl_xor(v, 2));
            v = fmaxf(v, __shfl_xor(v, 4));
            v = fmaxf(v, __shfl_xor(v, 8));
            if (cl == 0)
                atomicMax(&rowmax[brow + m * 16 + (rg << 2) + r], fkey(v));
        }

    // ---- flush colmax (batched, once per block) ----
    __syncthreads();
    #pragma unroll
    for (int i = 0; i < 16; ++i) {
        const int c = t + (i << 8);
        atomicMax(&colmax[scol + c], fkey(clds[c]));
    }
    #undef STAGEB
}

// ---------------- finalize: hinge + total sum ----------------
__global__ __launch_bounds__(1024) void finalize_kernel(
    const float* __restrict__ diag,
    const unsigned* __restrict__ rowmax,
    const unsigned* __restrict__ colmax,
    float* __restrict__ out) {
    __shared__ float red[1024];
    int t = threadIdx.x;
    float s = 0.f;
    for (int idx = t; idx < 2 * NN; idx += 1024) {
        int i = idx & (NN - 1);
        float mx = fdec((idx < NN) ? colmax[i] : rowmax[i]);
        s += fmaxf(mx + (MARGIN_F - diag[i]), 0.f);
    }
    red[t] = s;
    __syncthreads();
    for (int off = 512; off > 0; off >>= 1) {
        if (t < off) red[t] += red[t + off];
        __syncthreads();
    }
    if (t == 0) out[0] = red[0];
}

extern "C" void kernel_launch(void* const* d_in, const int* in_sizes, int n_in,
                              void* d_out, int out_size, void* d_ws, size_t ws_size,
                              hipStream_t stream) {
    const float* imgs = reinterpret_cast<const float*>(d_in[0]);
    const float* caps = reinterpret_cast<const float*>(d_in[1]);

    float* diag          = reinterpret_cast<float*>(d_ws);
    unsigned* rowmax     = reinterpret_cast<unsigned*>(diag + NN);
    unsigned* colmax     = rowmax + NN;
    unsigned char* imgs8 = reinterpret_cast<unsigned char*>(colmax + NN);
    unsigned char* caps8 = imgs8 + (size_t)NN * DD;

    fused_prep_kernel<<<NN / 4, 256, 0, stream>>>(imgs, caps, imgs8, caps8,
                                                  diag, rowmax, colmax);

    score_max_kernel<<<512, 256, 0, stream>>>(imgs8, caps8, diag,
                                              rowmax, colmax);

    finalize_kernel<<<1, 1024, 0, stream>>>(diag, rowmax, colmax,
                                            reinterpret_cast<float*>(d_out));
}

// Round 18
// 95.161 us; speedup vs baseline: 1.3814x; 1.3814x over previous
//
#include <hip/hip_runtime.h>
#include <hip/hip_bf16.h>
#include <hip/hip_fp8.h>
#include <stdint.h>
#include <math.h>

#define NN 16384
#define DD 256
#define MARGIN_F 0.2f

typedef __attribute__((ext_vector_type(8))) int int32x8;
typedef __attribute__((ext_vector_type(4))) float f32x4;

// monotone order-preserving float<->uint key (max via unsigned atomicMax)
__device__ inline unsigned fkey(float f) {
    unsigned b = __float_as_uint(f);
    return (b & 0x80000000u) ? ~b : (b | 0x80000000u);
}
__device__ inline float fdec(unsigned k) {
    return __uint_as_float((k & 0x80000000u) ? (k ^ 0x80000000u) : ~k);
}
#define NEG_INF_KEY 0x007FFFFFu   // fkey(-inf)

__device__ inline void gload16(const void* g, void* l) {
    __builtin_amdgcn_global_load_lds(
        (const __attribute__((address_space(1))) void*)g,
        (__attribute__((address_space(3))) void*)l, 16, 0, 0);
}

__device__ inline unsigned pk8(float4 v) {
    __hip_fp8_e4m3 q0(v.x), q1(v.y), q2(v.z), q3(v.w);
    return (unsigned)q0.__x | ((unsigned)q1.__x << 8) |
           ((unsigned)q2.__x << 16) | ((unsigned)q3.__x << 24);
}

// ---------------- fused prep: f32->fp8 e4m3 + diag + init maxes ------------
__global__ __launch_bounds__(256) void fused_prep_kernel(
    const float* __restrict__ imgs, const float* __restrict__ caps,
    unsigned char* __restrict__ imgs8, unsigned char* __restrict__ caps8,
    float* __restrict__ diag, unsigned* __restrict__ rowmax,
    unsigned* __restrict__ colmax) {
    const int i = (blockIdx.x << 2) + (threadIdx.x >> 6);
    const int l = threadIdx.x & 63;
    const float4* a4 = reinterpret_cast<const float4*>(imgs + (size_t)i * DD);
    const float4* b4 = reinterpret_cast<const float4*>(caps + (size_t)i * DD);
    float4 av = a4[l];
    float4 bv = b4[l];
    reinterpret_cast<unsigned*>(imgs8 + (size_t)i * DD)[l] = pk8(av);
    reinterpret_cast<unsigned*>(caps8 + (size_t)i * DD)[l] = pk8(bv);
    float s = av.x * bv.x + av.y * bv.y + av.z * bv.z + av.w * bv.w;
    #pragma unroll
    for (int off = 32; off > 0; off >>= 1) s += __shfl_down(s, off);
    if (l == 0) {
        diag[i] = s;
        rowmax[i] = NEG_INF_KEY;
        colmax[i] = NEG_INF_KEY;
    }
}

// ---------------- main: MX-fp8, B direct global->VGPR, zero in-loop sync ---
// 512 blocks = 128 row-panels(128) x 4 col-strips(4096). A panel (32KB fp8)
// staged once via gload_lds -> af[8][2] (64 VGPRs, full 128 rows per wave).
// B: each wave owns a 16-col slice per 64-col chunk; its fragment is 32
// CONTIGUOUS bytes/lane in global (fp8!), L2-resident -> load straight to
// VGPRs, register-double-buffered one chunk ahead (~1200cyc MFMA cover vs
// ~225cyc L2 latency). No B LDS staging, no ds_reads, NO BARRIERS in loop:
// waves desync and overlap pipes naturally. colmax cols are wave-exclusive
// -> plain LDS fmax; flushed after one final syncthreads.
__global__ __launch_bounds__(256, 2) void score_max_kernel(
    const unsigned char* __restrict__ imgs8,
    const unsigned char* __restrict__ caps8,
    const float* __restrict__ diag,
    unsigned* __restrict__ rowmax, unsigned* __restrict__ colmax) {

    __shared__ char lds[49152];   // [0,32K): A staging; [32K,48K): clds
    float* clds = reinterpret_cast<float*>(lds + 32768);

    const int bid   = blockIdx.x;
    const int panel = bid >> 2;
    const int strip = bid & 3;
    const int brow  = panel << 7;       // 128-row panel
    const int scol  = strip << 12;      // 4096-col strip

    const int t    = threadIdx.x;
    const int wid  = t >> 6;      // 0..3: col-slice owner
    const int lane = t & 63;
    const int rg   = lane >> 4;   // 0..3
    const int cl   = lane & 15;   // 0..15

    // ---- init clds (4096 floats) ----
    #pragma unroll
    for (int i = 0; i < 16; ++i) clds[t + (i << 8)] = -INFINITY;

    // ---- stage A panel (128 rows = 32KB) with 32B-pair XOR swizzle ----
    {
        const int sl = t & 15;
        const int rw = t >> 4;
        const int srcoff = (((sl >> 1) ^ (rw & 7)) << 5) + ((sl & 1) << 4);
        const unsigned char* src =
            imgs8 + (((size_t)(brow + rw)) << 8) + srcoff;
        #pragma unroll
        for (int i = 0; i < 8; ++i)
            gload16(src + ((size_t)i << 12), lds + t * 16 + i * 4096);
    }
    __syncthreads();

    // ---- A fragments: af[m][ks], row = m*16+cl (full 128 rows/wave) ----
    int32x8 af[8][2];
    #pragma unroll
    for (int m = 0; m < 8; ++m) {
        const int row = m * 16 + cl;
        #pragma unroll
        for (int ks = 0; ks < 2; ++ks)
            af[m][ks] = *reinterpret_cast<const int32x8*>(
                lds + row * 256 + (((rg + (ks << 2)) ^ (cl & 7)) << 5));
    }
    // no further LDS use except clds (wave-exclusive) -> no barrier needed

    float rmx[8][4];
    #pragma unroll
    for (int m = 0; m < 8; ++m)
        #pragma unroll
        for (int r = 0; r < 4; ++r) rmx[m][r] = -INFINITY;

    // ---- B base: this wave's col = scol + wid*16 + cl; 32B at rg*32,
    //      second K-half at +128; chunk h advances by 64 cols = +16384B ----
    const unsigned char* pb =
        caps8 + (((size_t)(scol + (wid << 4) + cl)) << 8) + (rg << 5);

    const f32x4 zv = (f32x4){0.f, 0.f, 0.f, 0.f};
    #define SCL 0x7F7F7F7F   // E8M0 exponent 127 = 1.0 in every byte

    // prologue: load chunk 0 fragments
    int32x8 b0 = *reinterpret_cast<const int32x8*>(pb);
    int32x8 b1 = *reinterpret_cast<const int32x8*>(pb + 128);

    for (int h = 0; h < 64; ++h) {
        const int cb = scol + (h << 6);
        const int hn = (h < 63) ? h + 1 : h;     // clamp: dead reload at tail
        const unsigned char* pn = pb + ((size_t)hn << 14);

        // issue next chunk's loads (L2 hit ~225cyc; covered by 16 MFMAs)
        int32x8 bn0 = *reinterpret_cast<const int32x8*>(pn);
        int32x8 bn1 = *reinterpret_cast<const int32x8*>(pn + 128);

        f32x4 acc[8];
        __builtin_amdgcn_s_setprio(1);
        #pragma unroll
        for (int m = 0; m < 8; ++m)
            acc[m] = __builtin_amdgcn_mfma_scale_f32_16x16x128_f8f6f4(
                af[m][0], b0, zv, 0, 0, 0, SCL, 0, SCL);
        #pragma unroll
        for (int m = 0; m < 8; ++m)
            acc[m] = __builtin_amdgcn_mfma_scale_f32_16x16x128_f8f6f4(
                af[m][1], b1, acc[m], 0, 0, 0, SCL, 0, SCL);
        __builtin_amdgcn_s_setprio(0);

        // ---- diagonal fix (exact f32); wave's cols = cfb..cfb+15 ----
        const int cfb = cb + (wid << 4);
        if (cfb < brow + 128 && cfb + 16 > brow) {
            #pragma unroll
            for (int m = 0; m < 8; ++m)
                #pragma unroll
                for (int r = 0; r < 4; ++r) {
                    const int gi = brow + m * 16 + (rg << 2) + r;
                    if (gi - cfb == cl) acc[m][r] = -diag[gi];
                }
        }

        // ---- running row-max ----
        #pragma unroll
        for (int m = 0; m < 8; ++m)
            #pragma unroll
            for (int r = 0; r < 4; ++r)
                rmx[m][r] = fmaxf(rmx[m][r], acc[m][r]);

        // ---- col-max: 32->1 reduce + 2 shfl, wave-exclusive LDS fmax ----
        {
            float v = fmaxf(fmaxf(acc[0][0], acc[0][1]),
                            fmaxf(acc[0][2], acc[0][3]));
            #pragma unroll
            for (int m = 1; m < 8; ++m)
                v = fmaxf(v, fmaxf(fmaxf(acc[m][0], acc[m][1]),
                                   fmaxf(acc[m][2], acc[m][3])));
            v = fmaxf(v, __shfl_xor(v, 16));
            v = fmaxf(v, __shfl_xor(v, 32));
            if (rg == 0) {
                const int c = cfb + cl - scol;
                clds[c] = fmaxf(clds[c], v);
            }
        }

        b0 = bn0;
        b1 = bn1;
    }

    // ---- row-max writeout (4 waves cover same rows -> global atomic) ----
    #pragma unroll
    for (int m = 0; m < 8; ++m)
        #pragma unroll
        for (int r = 0; r < 4; ++r) {
            float v = rmx[m][r];
            v = fmaxf(v, __shfl_xor(v, 1));
            v = fmaxf(v, __shfl_xor(v, 2));
            v = fmaxf(v, __shfl_xor(v, 4));
            v = fmaxf(v, __shfl_xor(v, 8));
            if (cl == 0)
                atomicMax(&rowmax[brow + m * 16 + (rg << 2) + r], fkey(v));
        }

    // ---- flush colmax (batched, once per block) ----
    __syncthreads();
    #pragma unroll
    for (int i = 0; i < 16; ++i) {
        const int c = t + (i << 8);
        atomicMax(&colmax[scol + c], fkey(clds[c]));
    }
}

// ---------------- finalize: hinge + total sum ----------------
__global__ __launch_bounds__(1024) void finalize_kernel(
    const float* __restrict__ diag,
    const unsigned* __restrict__ rowmax,
    const unsigned* __restrict__ colmax,
    float* __restrict__ out) {
    __shared__ float red[1024];
    int t = threadIdx.x;
    float s = 0.f;
    for (int idx = t; idx < 2 * NN; idx += 1024) {
        int i = idx & (NN - 1);
        float mx = fdec((idx < NN) ? colmax[i] : rowmax[i]);
        s += fmaxf(mx + (MARGIN_F - diag[i]), 0.f);
    }
    red[t] = s;
    __syncthreads();
    for (int off = 512; off > 0; off >>= 1) {
        if (t < off) red[t] += red[t + off];
        __syncthreads();
    }
    if (t == 0) out[0] = red[0];
}

extern "C" void kernel_launch(void* const* d_in, const int* in_sizes, int n_in,
                              void* d_out, int out_size, void* d_ws, size_t ws_size,
                              hipStream_t stream) {
    const float* imgs = reinterpret_cast<const float*>(d_in[0]);
    const float* caps = reinterpret_cast<const float*>(d_in[1]);

    float* diag          = reinterpret_cast<float*>(d_ws);
    unsigned* rowmax     = reinterpret_cast<unsigned*>(diag + NN);
    unsigned* colmax     = rowmax + NN;
    unsigned char* imgs8 = reinterpret_cast<unsigned char*>(colmax + NN);
    unsigned char* caps8 = imgs8 + (size_t)NN * DD;

    fused_prep_kernel<<<NN / 4, 256, 0, stream>>>(imgs, caps, imgs8, caps8,
                                                  diag, rowmax, colmax);

    score_max_kernel<<<512, 256, 0, stream>>>(imgs8, caps8, diag,
                                              rowmax, colmax);

    finalize_kernel<<<1, 1024, 0, stream>>>(diag, rowmax, colmax,
                                            reinterpret_cast<float*>(d_out));
}